// Round 17
// baseline (527.356 us; speedup 1.0000x reference)
//
#include <hip/hip_runtime.h>
#include <stdint.h>

#define PP 920
#define FF 5
#define BBATCH 4
#define CC 256
#define NN 4600          // FF*PP
#define HH 8
#define MROWS 18400      // BBATCH*NN
#define M2ROWS 92000     // BBATCH*NN*FF
#define SCALE 0.17677669529663687f

// EVIDENCE LOG:
//  - Inputs f32 bound BY SIZE; outputs f32: out=d_out[0:4710400), attn=[4710400:5446400).
//  - R12: flash 208us (16x16, conflicts 2.47e7). R13: VGPR cap -> spill. R14: L1-direct
//    gathers -> 500us. R15: no launch_bounds -> VGPR 64 -> spill 763us. R16: 32x32 +
//    launch_bounds(256): 227us, VGPR 184, conflicts 0, MfmaUtil 16% — latency-exposed
//    (occ 11%, 58 barriers, no overlap; MFMA floor ~35us, LDS floor ~50us).
//  - R17: T12 swapped-QKT + v_permlane32_swap (P stays in regs, Ps LDS deleted) +
//    T14 double-buffered K/V staging (load-early/write-late, ONE barrier per chunk).

typedef short bf16x8 __attribute__((ext_vector_type(8)));
typedef float f32x4 __attribute__((ext_vector_type(4)));
typedef float f32x16 __attribute__((ext_vector_type(16)));
typedef uint32_t u32;

#define MFMA16 __builtin_amdgcn_mfma_f32_16x16x32_bf16
#define MFMA32 __builtin_amdgcn_mfma_f32_32x32x16_bf16

__device__ __forceinline__ float b2f(unsigned short s){
  u32 u = ((u32)s) << 16; float f; __builtin_memcpy(&f, &u, 4); return f;
}
__device__ __forceinline__ unsigned short f2b(float f){
  u32 u; __builtin_memcpy(&u, &f, 4);
  u = (u + 0x7FFFu + ((u >> 16) & 1u)) >> 16;   // round-to-nearest-even
  return (unsigned short)u;
}

// ---------------- prep ----------------

__global__ void k17_cast(const float* __restrict__ in, short* __restrict__ out, int n){
  int i = blockIdx.x*256 + threadIdx.x;
  if (i < n) out[i] = (short)f2b(in[i]);
}

__global__ void k17_make_xb(const float* __restrict__ x, short* __restrict__ xb){
  int i = blockIdx.x*256 + threadIdx.x;       // one thread per 4 elems
  long e0 = (long)i*4;
  if (e0 >= (long)MROWS*CC) return;
  int row = (int)(e0 >> 8); int c = (int)(e0 & 255);
  int b = row / NN; int s = row - b*NN; int f = s / PP; int p = s - f*PP;
  const float4 v = *(const float4*)(x + ((size_t)(p*(BBATCH*FF) + b*FF + f))*CC + c);
  unsigned short o[4];
  o[0]=f2b(v.x); o[1]=f2b(v.y); o[2]=f2b(v.z); o[3]=f2b(v.w);
  *(ushort4*)(xb + e0) = *(ushort4*)o;
}

__global__ void k17_zero(short* p, int n){
  int i = blockIdx.x*256 + threadIdx.x;
  if (i < n) p[i] = 0;
}

// ---------------- MFMA GEMM (unchanged — passed R12-R16) ----------------
template<int MODE>
__launch_bounds__(256)
__global__ void k17_gemm(const short* __restrict__ A, const short* __restrict__ Bw,
                         short* __restrict__ Cout, float* __restrict__ FCout,
                         const float* __restrict__ bias,
                         int M, int lda, int ldc, float alpha)
{
  __shared__ short As[128][40];
  __shared__ short Bs[128][40];
  const int tid = threadIdx.x;
  const int m0 = blockIdx.x*128, n0 = blockIdx.y*128;
  const int w = tid >> 6, l = tid & 63;
  const int wm = (w >> 1)*64, wn = (w & 1)*64;
  const int lr = l & 15, lg = l >> 4;

  f32x4 acc[4][4] = {};

  for (int k0 = 0; k0 < 256; k0 += 32){
    #pragma unroll
    for (int i = 0; i < 2; i++){
      int v = tid + 256*i;               // 0..511
      int ar = v >> 2, as = (v & 3)*8;
      int grow = m0 + ar; if (grow >= M) grow = M - 1;
      *(uint4*)(&As[ar][as]) = *(const uint4*)(A + (size_t)grow*lda + k0 + as);
      *(uint4*)(&Bs[ar][as]) = *(const uint4*)(Bw + (size_t)(n0 + ar)*256 + k0 + as);
    }
    __syncthreads();
    bf16x8 af[4], bfr[4];
    #pragma unroll
    for (int i = 0; i < 4; i++) af[i]  = *(const bf16x8*)(&As[wm + i*16 + lr][lg*8]);
    #pragma unroll
    for (int j = 0; j < 4; j++) bfr[j] = *(const bf16x8*)(&Bs[wn + j*16 + lr][lg*8]);
    #pragma unroll
    for (int i = 0; i < 4; i++)
      #pragma unroll
      for (int j = 0; j < 4; j++)
        acc[i][j] = MFMA16(af[i], bfr[j], acc[i][j], 0, 0, 0);
    __syncthreads();
  }

  #pragma unroll
  for (int i = 0; i < 4; i++){
    #pragma unroll
    for (int r = 0; r < 4; r++){
      int m = m0 + wm + i*16 + lg*4 + r;
      if (m >= M) continue;
      #pragma unroll
      for (int j = 0; j < 4; j++){
        int n = n0 + wn + j*16 + lr;
        float v = acc[i][j][r]*alpha;
        if (MODE == 1){
          v += bias[n];
          int b = m / NN, s = m - b*NN; int f = s / PP, p = s - f*PP;
          FCout[(size_t)(p*(BBATCH*FF) + b*FF + f)*CC + n] = v;    // f32 store
        } else {
          Cout[(size_t)m*ldc + n] = (short)f2b(v);
        }
      }
    }
  }
}

// ---------------- V transpose (unchanged) ----------------
__launch_bounds__(256)
__global__ void k17_vt(const short* __restrict__ qkv, short* __restrict__ vt){
  __shared__ short t[64][80];
  const int p0 = blockIdx.x*64;
  const int c0 = blockIdx.y*64;
  const int bf = blockIdx.z;
  const int b = bf / FF, f = bf - b*FF;
  const int tid = threadIdx.x;
  #pragma unroll
  for (int i = 0; i < 2; i++){
    int v = tid + 256*i;                 // 0..511
    int pr = v >> 3, sg = (v & 7)*8;
    uint4 val = make_uint4(0,0,0,0);
    int p = p0 + pr;
    if (p < PP)
      val = *(const uint4*)(qkv + ((size_t)(b*NN + f*PP + p))*768 + 512 + c0 + sg);
    *(uint4*)(&t[pr][sg]) = val;
  }
  __syncthreads();
  #pragma unroll
  for (int i = 0; i < 2; i++){
    int v = tid + 256*i;
    int cr = v & 63, pg = v >> 6;        // pg 0..7
    int pbase = p0 + pg*8;
    if (pbase < 928){
      unsigned short o[8];
      #pragma unroll
      for (int jj = 0; jj < 8; jj++) o[jj] = (unsigned short)t[pg*8 + jj][cr];
      *(uint4*)(vt + ((size_t)(bf*CC + c0 + cr))*928 + pbase) = *(uint4*)o;
    }
  }
}

// ---------------- Stage-1 flash v6: swapped QK^T + permlane P, dbuf K/V, 1 barrier/chunk ----------------
// grid (36, 5, 4). 4 waves; wave w owns q rows qt*128 + w*32 .. +31.
// Swapped QK^T: D = MFMA32(K_frag, Q_frag) -> lane(cl,hi) holds S[q=cl][key0 + kmap(r,hi)],
// kmap(r,hi) = (r&3)+8*(r>>2)+4*hi. PV A-frags assembled in-register with
// v_permlane32_swap_b32 (dst-hi <-> src-lo). O epilogue layout identical to validated R15/16.
__launch_bounds__(256)
__global__ void k17_flash(const short* __restrict__ qkv, const short* __restrict__ vt,
                          short* __restrict__ x1, short* __restrict__ xd)
{
  __shared__ short Ks[2][32][264];   // 2 x (32 keys x 256 c, +8 pad) = 33.8 KB
  __shared__ short Vs[2][256][40];   // 2 x (256 c x 32 keys, +8 pad) = 41.0 KB

  const int qt = blockIdx.x, f = blockIdx.y, b = blockIdx.z;
  const int tid = threadIdx.x, l = tid & 63;
  const int w = tid >> 6;
  const int cl = l & 31, hi = l >> 5;
  const int qbase = qt*128 + w*32;

  // Q fragments (row = cl, c-slice = kk*16 + hi*8) — validated layout
  bf16x8 qa[16];
  {
    int qrow = qbase + cl; if (qrow > NN - 1) qrow = NN - 1;
    const short* qp = qkv + (size_t)(b*NN + qrow)*768 + hi*8;
    #pragma unroll
    for (int kk = 0; kk < 16; kk++) qa[kk] = *(const bf16x8*)(qp + kk*16);
  }

  f32x16 o[8] = {};
  float den = 0.f;                 // partial denominator for q = cl (this lane's 16 key-slots)

  const size_t krow0 = (size_t)(b*NN + f*PP)*768 + 256;
  const short* vtp = vt + (size_t)((b*FF + f)*CC)*928;

  // staging registers (T14: load early, write late)
  uint4 kreg[4], vreg[4];
  const int skr = tid >> 5;               // not used; kept simple below

  // ---- stage load helper (into regs) ----
  auto stage_load = [&](int ch){
    const int key0 = ch*32;
    #pragma unroll
    for (int i = 0; i < 4; i++){
      int v = tid + 256*i;                // 0..1023
      int kr = v >> 5, ks = (v & 31)*8;
      kreg[i] = *(const uint4*)(qkv + krow0 + (size_t)(key0 + kr)*768 + ks);
    }
    const short* vp = vtp + (size_t)tid*928 + key0;
    #pragma unroll
    for (int i = 0; i < 4; i++) vreg[i] = *(const uint4*)(vp + i*8);
  };
  // ---- stage write helper (regs -> LDS buffer) ----
  auto stage_write = [&](int buf){
    #pragma unroll
    for (int i = 0; i < 4; i++){
      int v = tid + 256*i;
      int kr = v >> 5, ks = (v & 31)*8;
      *(uint4*)(&Ks[buf][kr][ks]) = kreg[i];
    }
    #pragma unroll
    for (int i = 0; i < 4; i++) *(uint4*)(&Vs[buf][tid][i*8]) = vreg[i];
  };

  // prologue: fill buffer 0
  stage_load(0);
  stage_write(0);

  for (int ch = 0; ch < 29; ch++){
    const int cur = ch & 1;
    const int key0 = ch*32;
    __syncthreads();                       // buf[cur] ready; prev reads of buf[cur^1] done

    if (ch < 28) stage_load(ch + 1);       // issue global loads now; hide under compute

    // --- swapped QK^T: s[r] = S[q=cl][key0 + kmap(r,hi)] ---
    f32x16 s = {};
    #pragma unroll
    for (int kk = 0; kk < 16; kk++){
      bf16x8 kb = *(const bf16x8*)(&Ks[cur][cl][kk*16 + hi*8]);
      s = MFMA32(kb, qa[kk], s, 0, 0, 0);
    }

    // --- softmax numerators in-register (fixed-max: |logit| bounded ~1.7) ---
    float p[16];
    #pragma unroll
    for (int r = 0; r < 16; r++){
      int key = key0 + (r & 3) + 8*(r >> 2) + 4*hi;
      float v = (key < PP) ? s[r]*SCALE : -1e30f;
      p[r] = __expf(v);
      den += p[r];
    }

    // --- pack to bf16 pairs; 4 permlane swaps assemble both PV A-frags ---
    u32 u0 = (u32)f2b(p[0])  | ((u32)f2b(p[1])  << 16);
    u32 u1 = (u32)f2b(p[2])  | ((u32)f2b(p[3])  << 16);
    u32 u2 = (u32)f2b(p[4])  | ((u32)f2b(p[5])  << 16);
    u32 u3 = (u32)f2b(p[6])  | ((u32)f2b(p[7])  << 16);
    u32 u4 = (u32)f2b(p[8])  | ((u32)f2b(p[9])  << 16);
    u32 u5 = (u32)f2b(p[10]) | ((u32)f2b(p[11]) << 16);
    u32 u6 = (u32)f2b(p[12]) | ((u32)f2b(p[13]) << 16);
    u32 u7 = (u32)f2b(p[14]) | ((u32)f2b(p[15]) << 16);
    // dst-hi <-> src-lo: (u0,u2)->w0,w2 ; (u1,u3)->w1,w3 ; keys 16-31 likewise
    asm("v_permlane32_swap_b32 %0, %1" : "+v"(u0), "+v"(u2));
    asm("v_permlane32_swap_b32 %0, %1" : "+v"(u1), "+v"(u3));
    asm("v_permlane32_swap_b32 %0, %1" : "+v"(u4), "+v"(u6));
    asm("v_permlane32_swap_b32 %0, %1" : "+v"(u5), "+v"(u7));
    u32 f1[4] = {u0, u1, u2, u3};
    u32 f2[4] = {u4, u5, u6, u7};
    bf16x8 pa0, pa1;
    __builtin_memcpy(&pa0, f1, 16);        // A-frag keys 0-15  (row=q=cl)
    __builtin_memcpy(&pa1, f2, 16);        // A-frag keys 16-31

    // --- PV: O += P @ V ---
    #pragma unroll
    for (int ct = 0; ct < 8; ct++){
      bf16x8 vb0 = *(const bf16x8*)(&Vs[cur][ct*32 + cl][hi*8]);
      bf16x8 vb1 = *(const bf16x8*)(&Vs[cur][ct*32 + cl][16 + hi*8]);
      o[ct] = MFMA32(pa0, vb0, o[ct], 0, 0, 0);
      o[ct] = MFMA32(pa1, vb1, o[ct], 0, 0, 0);
    }

    if (ch < 28) stage_write(cur ^ 1);     // write next tile into idle buffer (post-compute)
  }

  // ---- epilogue ----
  den += __shfl_xor(den, 32);              // combine hi/lo key-halves: full den for q=cl
  float invd = 1.f/den;
  #pragma unroll
  for (int r = 0; r < 16; r++){
    int qr = (r & 3) + 8*(r >> 2) + 4*hi;  // q-row of o reg r (C/D mapping)
    float inv = __shfl(invd, qr);          // den lives at lane qr (q = cl = qr)
    int srow = qbase + qr;
    if (srow >= NN) continue;
    bool dg = (srow/PP == f);
    size_t x1base = ((size_t)(b*NN + srow)*FF + f)*CC;
    size_t xdbase = (size_t)(b*NN + srow)*CC;
    #pragma unroll
    for (int ct = 0; ct < 8; ct++){
      short val = (short)f2b(o[ct][r]*inv);
      x1[x1base + ct*32 + cl] = val;
      if (dg) xd[xdbase + ct*32 + cl] = val;
    }
  }
}

// ---------------- Stage-2 attention (unchanged — passed R12-R16) ----------------
__launch_bounds__(256)
__global__ void k17_attn2(const short* __restrict__ q2b, const short* __restrict__ k2v2,
                          float* __restrict__ attnp, short* __restrict__ x2)
{
  int idx = blockIdx.x*256 + threadIdx.x;
  if (idx >= MROWS*HH) return;
  const int h = idx & 7; const int row = idx >> 3;   // row = b*N + s

  float qv[32];
  {
    const short* qp = q2b + (size_t)row*CC + h*32;
    #pragma unroll
    for (int s4 = 0; s4 < 4; s4++){
      uint4 u = *(const uint4*)(qp + s4*8);
      const unsigned short* sp = (const unsigned short*)&u;
      #pragma unroll
      for (int j = 0; j < 8; j++) qv[s4*8 + j] = b2f(sp[j]);
    }
  }

  float lgt[FF];
  #pragma unroll
  for (int f = 0; f < FF; f++){
    const short* kp = k2v2 + ((size_t)row*FF + f)*512 + h*32;
    float a = 0.f;
    #pragma unroll
    for (int s4 = 0; s4 < 4; s4++){
      uint4 u = *(const uint4*)(kp + s4*8);
      const unsigned short* sp = (const unsigned short*)&u;
      #pragma unroll
      for (int j = 0; j < 8; j++) a += qv[s4*8 + j]*b2f(sp[j]);
    }
    lgt[f] = a;
  }

  float mx = lgt[0];
  #pragma unroll
  for (int f = 1; f < FF; f++) mx = fmaxf(mx, lgt[f]);
  float pr[FF], ps = 0.f;
  #pragma unroll
  for (int f = 0; f < FF; f++){ pr[f] = __expf(lgt[f] - mx); ps += pr[f]; }
  float inv = 1.f/ps;

  const int b = row / NN; const int s = row - b*NN;
  size_t ab = (((size_t)(b*HH + h))*NN + s)*FF;
  #pragma unroll
  for (int f = 0; f < FF; f++) attnp[ab + f] = pr[f]*inv;   // f32 store

  float xa[32] = {};
  #pragma unroll
  for (int f = 0; f < FF; f++){
    const short* vp = k2v2 + ((size_t)row*FF + f)*512 + 256 + h*32;
    float wgt = pr[f]*inv;
    #pragma unroll
    for (int s4 = 0; s4 < 4; s4++){
      uint4 u = *(const uint4*)(vp + s4*8);
      const unsigned short* sp = (const unsigned short*)&u;
      #pragma unroll
      for (int j = 0; j < 8; j++) xa[s4*8 + j] += wgt*b2f(sp[j]);
    }
  }
  #pragma unroll
  for (int s4 = 0; s4 < 4; s4++){
    unsigned short o[8];
    #pragma unroll
    for (int j = 0; j < 8; j++) o[j] = f2b(xa[s4*8 + j]);
    *(uint4*)(x2 + (size_t)row*CC + h*32 + s4*8) = *(uint4*)o;
  }
}

// ---------------- launcher ----------------
extern "C" void kernel_launch(void* const* d_in, const int* in_sizes, int n_in,
                              void* d_out, int out_size, void* d_ws, size_t ws_size,
                              hipStream_t stream)
{
  // bind inputs BY SIZE (validated rounds 10-16)
  int ix=-1, iwqkv=-1, iwpq=-1, iwpkv=-1, iwproj=-1, ib=-1;
  for (int i = 0; i < n_in; i++){
    switch (in_sizes[i]){
      case 4710400: ix = i; break;
      case 196608:  iwqkv = i; break;
      case 131072:  iwpkv = i; break;
      case 256:     ib = i; break;
      case 65536:   if (iwpq < 0) iwpq = i; else iwproj = i; break;
      default: break;
    }
  }
  if (ix < 0 || iwqkv < 0 || iwpq < 0 || iwpkv < 0 || iwproj < 0 || ib < 0){
    ix=0; iwqkv=1; iwpq=2; iwpkv=3; iwproj=4; ib=5;
  }
  const float* x     = (const float*)d_in[ix];
  const float* Wqkv  = (const float*)d_in[iwqkv];
  const float* Wpq   = (const float*)d_in[iwpq];
  const float* Wpkv  = (const float*)d_in[iwpkv];
  const float* Wproj = (const float*)d_in[iwproj];
  const float* bproj = (const float*)d_in[ib];

  char* ws = (char*)d_ws;
  if (ws_size < 208269312ULL) return;

  short* wq    = (short*)(ws + 0);               // 768*256
  short* wpq   = (short*)(ws + 393216);          // 256*256
  short* wpkv  = (short*)(ws + 524288);          // 512*256
  short* wprj  = (short*)(ws + 786432);          // 256*256
  short* xb    = (short*)(ws + 917504);          // 18400x256
  short* qkv   = (short*)(ws + 10338304);        // 18408x768 (8 slack rows zeroed)
  short* vt    = (short*)(ws + 38612992);        // 20x256x928
  short* x1    = (short*)(ws + 48115712);        // 92000x256
  short* xd    = (short*)(ws + 95219712);        // 18400x256
  short* k2v2  = (short*)(ws + 104640512);       // 92000x512
  short* q2b   = (short*)(ws + 198848512);       // 18400x256 -> end 208,269,312
  short* x2    = xb;                             // alias: xb dead after QKV GEMM

  float* outp  = (float*)d_out;                  // f32 out   [0 : 4,710,400)
  float* attnp = outp + 4710400;                 // f32 attn  [4,710,400 : 5,446,400)

  k17_cast<<<dim3(768), dim3(256), 0, stream>>>(Wqkv,  wq,   196608);
  k17_cast<<<dim3(256), dim3(256), 0, stream>>>(Wpq,   wpq,  65536);
  k17_cast<<<dim3(512), dim3(256), 0, stream>>>(Wpkv,  wpkv, 131072);
  k17_cast<<<dim3(256), dim3(256), 0, stream>>>(Wproj, wprj, 65536);
  k17_make_xb<<<dim3(4600), dim3(256), 0, stream>>>(x, xb);
  k17_zero<<<dim3(24), dim3(256), 0, stream>>>(qkv + (size_t)MROWS*768, 6144);

  // qkv = xb @ Wqkv^T           (MFMA)
  k17_gemm<0><<<dim3(144, 6), dim3(256), 0, stream>>>(xb, wq, qkv, nullptr, nullptr, MROWS, 256, 768, 1.0f);
  // V transpose for flash
  k17_vt<<<dim3(15, 4, 20), dim3(256), 0, stream>>>(qkv, vt);
  // stage-1 flash attention v6  (swapped-QKT + permlane P, dbuf, 1 barrier/chunk)
  k17_flash<<<dim3(36, 5, 4), dim3(256), 0, stream>>>(qkv, vt, x1, xd);
  // kv2 = x1 @ Wpkv^T           (MFMA)
  k17_gemm<0><<<dim3(719, 4), dim3(256), 0, stream>>>(x1, wpkv, k2v2, nullptr, nullptr, M2ROWS, 256, 512, 1.0f);
  // q2 = xd @ Wpq^T * scale     (MFMA)
  k17_gemm<0><<<dim3(144, 2), dim3(256), 0, stream>>>(xd, wpq, q2b, nullptr, nullptr, MROWS, 256, 256, SCALE);
  // stage-2 attention (f32 attn, bf16 x2)
  k17_attn2<<<dim3(575), dim3(256), 0, stream>>>(q2b, k2v2, attnp, x2);
  // out = x2 @ Wproj^T + bias   (MFMA, f32 permuted store)
  k17_gemm<1><<<dim3(144, 2), dim3(256), 0, stream>>>(x2, wprj, nullptr, outp, bproj, MROWS, 256, 256, 1.0f);
}

// Round 18
// 420.770 us; speedup vs baseline: 1.2533x; 1.2533x over previous
//
#include <hip/hip_runtime.h>
#include <stdint.h>

#define PP 920
#define FF 5
#define BBATCH 4
#define CC 256
#define NN 4600          // FF*PP
#define HH 8
#define MROWS 18400      // BBATCH*NN
#define M2ROWS 92000     // BBATCH*NN*FF
#define SCALE 0.17677669529663687f

// EVIDENCE LOG:
//  - Inputs f32 bound BY SIZE; outputs f32: out=d_out[0:4710400), attn=[4710400:5446400).
//  - R12: flash 208us (16x16). R13/R15: VGPR spill regressions. R14: L1-direct gathers.
//  - R16 (32x32 + launch_bounds(256)): flash 227us, VGPR 184, conflicts 0, no spill. BASE.
//  - R17 (T12 + T14 bundled): PASS (T12 swapped-QKT/permlane/epilogue HW-VALIDATED) but
//    reg-staged dbuf pushed live set ~250 vs 152 allocated -> 50MB spill stores
//    (WRITE 55->107MB) -> 406us. Lesson: one variable; reg-staging blew the budget.
//  - R18 = R16 + T12 ONLY: P in registers (no Ps LDS), direct LDS staging, 2 barriers.
//    No-spill signal: WRITE_SIZE ~55MB.

typedef short bf16x8 __attribute__((ext_vector_type(8)));
typedef float f32x4 __attribute__((ext_vector_type(4)));
typedef float f32x16 __attribute__((ext_vector_type(16)));
typedef uint32_t u32;

#define MFMA16 __builtin_amdgcn_mfma_f32_16x16x32_bf16
#define MFMA32 __builtin_amdgcn_mfma_f32_32x32x16_bf16

__device__ __forceinline__ float b2f(unsigned short s){
  u32 u = ((u32)s) << 16; float f; __builtin_memcpy(&f, &u, 4); return f;
}
__device__ __forceinline__ unsigned short f2b(float f){
  u32 u; __builtin_memcpy(&u, &f, 4);
  u = (u + 0x7FFFu + ((u >> 16) & 1u)) >> 16;   // round-to-nearest-even
  return (unsigned short)u;
}

// ---------------- prep ----------------

__global__ void k18_cast(const float* __restrict__ in, short* __restrict__ out, int n){
  int i = blockIdx.x*256 + threadIdx.x;
  if (i < n) out[i] = (short)f2b(in[i]);
}

__global__ void k18_make_xb(const float* __restrict__ x, short* __restrict__ xb){
  int i = blockIdx.x*256 + threadIdx.x;       // one thread per 4 elems
  long e0 = (long)i*4;
  if (e0 >= (long)MROWS*CC) return;
  int row = (int)(e0 >> 8); int c = (int)(e0 & 255);
  int b = row / NN; int s = row - b*NN; int f = s / PP; int p = s - f*PP;
  const float4 v = *(const float4*)(x + ((size_t)(p*(BBATCH*FF) + b*FF + f))*CC + c);
  unsigned short o[4];
  o[0]=f2b(v.x); o[1]=f2b(v.y); o[2]=f2b(v.z); o[3]=f2b(v.w);
  *(ushort4*)(xb + e0) = *(ushort4*)o;
}

__global__ void k18_zero(short* p, int n){
  int i = blockIdx.x*256 + threadIdx.x;
  if (i < n) p[i] = 0;
}

// ---------------- MFMA GEMM (unchanged — passed R12-R17) ----------------
template<int MODE>
__launch_bounds__(256)
__global__ void k18_gemm(const short* __restrict__ A, const short* __restrict__ Bw,
                         short* __restrict__ Cout, float* __restrict__ FCout,
                         const float* __restrict__ bias,
                         int M, int lda, int ldc, float alpha)
{
  __shared__ short As[128][40];
  __shared__ short Bs[128][40];
  const int tid = threadIdx.x;
  const int m0 = blockIdx.x*128, n0 = blockIdx.y*128;
  const int w = tid >> 6, l = tid & 63;
  const int wm = (w >> 1)*64, wn = (w & 1)*64;
  const int lr = l & 15, lg = l >> 4;

  f32x4 acc[4][4] = {};

  for (int k0 = 0; k0 < 256; k0 += 32){
    #pragma unroll
    for (int i = 0; i < 2; i++){
      int v = tid + 256*i;               // 0..511
      int ar = v >> 2, as = (v & 3)*8;
      int grow = m0 + ar; if (grow >= M) grow = M - 1;
      *(uint4*)(&As[ar][as]) = *(const uint4*)(A + (size_t)grow*lda + k0 + as);
      *(uint4*)(&Bs[ar][as]) = *(const uint4*)(Bw + (size_t)(n0 + ar)*256 + k0 + as);
    }
    __syncthreads();
    bf16x8 af[4], bfr[4];
    #pragma unroll
    for (int i = 0; i < 4; i++) af[i]  = *(const bf16x8*)(&As[wm + i*16 + lr][lg*8]);
    #pragma unroll
    for (int j = 0; j < 4; j++) bfr[j] = *(const bf16x8*)(&Bs[wn + j*16 + lr][lg*8]);
    #pragma unroll
    for (int i = 0; i < 4; i++)
      #pragma unroll
      for (int j = 0; j < 4; j++)
        acc[i][j] = MFMA16(af[i], bfr[j], acc[i][j], 0, 0, 0);
    __syncthreads();
  }

  #pragma unroll
  for (int i = 0; i < 4; i++){
    #pragma unroll
    for (int r = 0; r < 4; r++){
      int m = m0 + wm + i*16 + lg*4 + r;
      if (m >= M) continue;
      #pragma unroll
      for (int j = 0; j < 4; j++){
        int n = n0 + wn + j*16 + lr;
        float v = acc[i][j][r]*alpha;
        if (MODE == 1){
          v += bias[n];
          int b = m / NN, s = m - b*NN; int f = s / PP, p = s - f*PP;
          FCout[(size_t)(p*(BBATCH*FF) + b*FF + f)*CC + n] = v;    // f32 store
        } else {
          Cout[(size_t)m*ldc + n] = (short)f2b(v);
        }
      }
    }
  }
}

// ---------------- V transpose (unchanged) ----------------
__launch_bounds__(256)
__global__ void k18_vt(const short* __restrict__ qkv, short* __restrict__ vt){
  __shared__ short t[64][80];
  const int p0 = blockIdx.x*64;
  const int c0 = blockIdx.y*64;
  const int bf = blockIdx.z;
  const int b = bf / FF, f = bf - b*FF;
  const int tid = threadIdx.x;
  #pragma unroll
  for (int i = 0; i < 2; i++){
    int v = tid + 256*i;                 // 0..511
    int pr = v >> 3, sg = (v & 7)*8;
    uint4 val = make_uint4(0,0,0,0);
    int p = p0 + pr;
    if (p < PP)
      val = *(const uint4*)(qkv + ((size_t)(b*NN + f*PP + p))*768 + 512 + c0 + sg);
    *(uint4*)(&t[pr][sg]) = val;
  }
  __syncthreads();
  #pragma unroll
  for (int i = 0; i < 2; i++){
    int v = tid + 256*i;
    int cr = v & 63, pg = v >> 6;        // pg 0..7
    int pbase = p0 + pg*8;
    if (pbase < 928){
      unsigned short o[8];
      #pragma unroll
      for (int jj = 0; jj < 8; jj++) o[jj] = (unsigned short)t[pg*8 + jj][cr];
      *(uint4*)(vt + ((size_t)(bf*CC + c0 + cr))*928 + pbase) = *(uint4*)o;
    }
  }
}

// ---------------- Stage-1 flash v7 = R16 structure + T12 (P in registers) ----------------
// grid (36, 5, 4). 4 waves; wave w owns q rows qt*128 + w*32 .. +31.
// Swapped QK^T (HW-validated R17): D = MFMA32(K_frag, Q_frag) -> lane(cl,hi) holds
// S[q=cl][key0 + (r&3)+8*(r>>2)+4*hi]. P packed to bf16, 4x v_permlane32_swap_b32
// assembles both PV A-frags in-register. Staging/barriers identical to R16.
__launch_bounds__(256)
__global__ void k18_flash(const short* __restrict__ qkv, const short* __restrict__ vt,
                          short* __restrict__ x1, short* __restrict__ xd)
{
  __shared__ short Ks[32][264];     // 32 keys x 256 c (+8 pad)   16.9 KB
  __shared__ short Vs[256][40];     // 256 c x 32 keys (+8 pad)   20.5 KB

  const int qt = blockIdx.x, f = blockIdx.y, b = blockIdx.z;
  const int tid = threadIdx.x, l = tid & 63;
  const int w = tid >> 6;
  const int cl = l & 31, hi = l >> 5;
  const int qbase = qt*128 + w*32;

  // Q fragments (row = cl, c-slice = kk*16 + hi*8) — validated layout
  bf16x8 qa[16];
  {
    int qrow = qbase + cl; if (qrow > NN - 1) qrow = NN - 1;
    const short* qp = qkv + (size_t)(b*NN + qrow)*768 + hi*8;
    #pragma unroll
    for (int kk = 0; kk < 16; kk++) qa[kk] = *(const bf16x8*)(qp + kk*16);
  }

  f32x16 o[8] = {};
  float den = 0.f;                 // partial denominator for q = cl (this lane's 16 key-slots)

  const size_t krow0 = (size_t)(b*NN + f*PP)*768 + 256;
  const short* vtp = vt + (size_t)((b*FF + f)*CC)*928;

  for (int ch = 0; ch < 29; ch++){
    const int key0 = ch*32;
    // stage K chunk (32 keys x 256 c) — coalesced direct global->LDS (R16 pattern)
    #pragma unroll
    for (int i = 0; i < 4; i++){
      int v = tid + 256*i;                   // 0..1023
      int kr = v >> 5, ks = (v & 31)*8;
      *(uint4*)(&Ks[kr][ks]) = *(const uint4*)(qkv + krow0 + (size_t)(key0 + kr)*768 + ks);
    }
    // stage V^T chunk (256 c x 32 keys) — one 64B line per thread
    {
      const short* vp = vtp + (size_t)tid*928 + key0;
      #pragma unroll
      for (int i = 0; i < 4; i++)
        *(uint4*)(&Vs[tid][i*8]) = *(const uint4*)(vp + i*8);
    }
    __syncthreads();

    // swapped QK^T: s[r] = S[q=cl][key0 + (r&3)+8*(r>>2)+4*hi]
    f32x16 s = {};
    #pragma unroll
    for (int kk = 0; kk < 16; kk++){
      bf16x8 kb = *(const bf16x8*)(&Ks[cl][kk*16 + hi*8]);
      s = MFMA32(kb, qa[kk], s, 0, 0, 0);
    }

    // softmax numerators in-register (fixed-max: |logit| bounded ~1.7)
    float p[16];
    #pragma unroll
    for (int r = 0; r < 16; r++){
      int key = key0 + (r & 3) + 8*(r >> 2) + 4*hi;
      float v = (key < PP) ? s[r]*SCALE : -1e30f;
      p[r] = __expf(v);
      den += p[r];
    }

    // pack to bf16 pairs; 4 permlane swaps assemble both PV A-frags (HW-validated R17)
    u32 u0 = (u32)f2b(p[0])  | ((u32)f2b(p[1])  << 16);
    u32 u1 = (u32)f2b(p[2])  | ((u32)f2b(p[3])  << 16);
    u32 u2 = (u32)f2b(p[4])  | ((u32)f2b(p[5])  << 16);
    u32 u3 = (u32)f2b(p[6])  | ((u32)f2b(p[7])  << 16);
    u32 u4 = (u32)f2b(p[8])  | ((u32)f2b(p[9])  << 16);
    u32 u5 = (u32)f2b(p[10]) | ((u32)f2b(p[11]) << 16);
    u32 u6 = (u32)f2b(p[12]) | ((u32)f2b(p[13]) << 16);
    u32 u7 = (u32)f2b(p[14]) | ((u32)f2b(p[15]) << 16);
    asm("v_permlane32_swap_b32 %0, %1" : "+v"(u0), "+v"(u2));
    asm("v_permlane32_swap_b32 %0, %1" : "+v"(u1), "+v"(u3));
    asm("v_permlane32_swap_b32 %0, %1" : "+v"(u4), "+v"(u6));
    asm("v_permlane32_swap_b32 %0, %1" : "+v"(u5), "+v"(u7));
    u32 fA[4] = {u0, u1, u2, u3};
    u32 fB[4] = {u4, u5, u6, u7};
    bf16x8 pa0, pa1;
    __builtin_memcpy(&pa0, fA, 16);        // A-frag keys 0-15  (row=q=cl)
    __builtin_memcpy(&pa1, fB, 16);        // A-frag keys 16-31

    // PV: O += P @ V
    #pragma unroll
    for (int ct = 0; ct < 8; ct++){
      bf16x8 vb0 = *(const bf16x8*)(&Vs[ct*32 + cl][hi*8]);
      bf16x8 vb1 = *(const bf16x8*)(&Vs[ct*32 + cl][16 + hi*8]);
      o[ct] = MFMA32(pa0, vb0, o[ct], 0, 0, 0);
      o[ct] = MFMA32(pa1, vb1, o[ct], 0, 0, 0);
    }
    __syncthreads();   // protect Ks/Vs before next staging
  }

  // epilogue (HW-validated R17): combine hi/lo key-halves, broadcast per-q den
  den += __shfl_xor(den, 32);
  float invd = 1.f/den;
  #pragma unroll
  for (int r = 0; r < 16; r++){
    int qr = (r & 3) + 8*(r >> 2) + 4*hi;  // q-row of o reg r (C/D mapping)
    float inv = __shfl(invd, qr);          // den for q=qr lives at lane qr
    int srow = qbase + qr;
    if (srow >= NN) continue;
    bool dg = (srow/PP == f);
    size_t x1base = ((size_t)(b*NN + srow)*FF + f)*CC;
    size_t xdbase = (size_t)(b*NN + srow)*CC;
    #pragma unroll
    for (int ct = 0; ct < 8; ct++){
      short val = (short)f2b(o[ct][r]*inv);
      x1[x1base + ct*32 + cl] = val;
      if (dg) xd[xdbase + ct*32 + cl] = val;
    }
  }
}

// ---------------- Stage-2 attention (unchanged — passed R12-R17) ----------------
__launch_bounds__(256)
__global__ void k18_attn2(const short* __restrict__ q2b, const short* __restrict__ k2v2,
                          float* __restrict__ attnp, short* __restrict__ x2)
{
  int idx = blockIdx.x*256 + threadIdx.x;
  if (idx >= MROWS*HH) return;
  const int h = idx & 7; const int row = idx >> 3;   // row = b*N + s

  float qv[32];
  {
    const short* qp = q2b + (size_t)row*CC + h*32;
    #pragma unroll
    for (int s4 = 0; s4 < 4; s4++){
      uint4 u = *(const uint4*)(qp + s4*8);
      const unsigned short* sp = (const unsigned short*)&u;
      #pragma unroll
      for (int j = 0; j < 8; j++) qv[s4*8 + j] = b2f(sp[j]);
    }
  }

  float lgt[FF];
  #pragma unroll
  for (int f = 0; f < FF; f++){
    const short* kp = k2v2 + ((size_t)row*FF + f)*512 + h*32;
    float a = 0.f;
    #pragma unroll
    for (int s4 = 0; s4 < 4; s4++){
      uint4 u = *(const uint4*)(kp + s4*8);
      const unsigned short* sp = (const unsigned short*)&u;
      #pragma unroll
      for (int j = 0; j < 8; j++) a += qv[s4*8 + j]*b2f(sp[j]);
    }
    lgt[f] = a;
  }

  float mx = lgt[0];
  #pragma unroll
  for (int f = 1; f < FF; f++) mx = fmaxf(mx, lgt[f]);
  float pr[FF], ps = 0.f;
  #pragma unroll
  for (int f = 0; f < FF; f++){ pr[f] = __expf(lgt[f] - mx); ps += pr[f]; }
  float inv = 1.f/ps;

  const int b = row / NN; const int s = row - b*NN;
  size_t ab = (((size_t)(b*HH + h))*NN + s)*FF;
  #pragma unroll
  for (int f = 0; f < FF; f++) attnp[ab + f] = pr[f]*inv;   // f32 store

  float xa[32] = {};
  #pragma unroll
  for (int f = 0; f < FF; f++){
    const short* vp = k2v2 + ((size_t)row*FF + f)*512 + 256 + h*32;
    float wgt = pr[f]*inv;
    #pragma unroll
    for (int s4 = 0; s4 < 4; s4++){
      uint4 u = *(const uint4*)(vp + s4*8);
      const unsigned short* sp = (const unsigned short*)&u;
      #pragma unroll
      for (int j = 0; j < 8; j++) xa[s4*8 + j] += wgt*b2f(sp[j]);
    }
  }
  #pragma unroll
  for (int s4 = 0; s4 < 4; s4++){
    unsigned short o[8];
    #pragma unroll
    for (int j = 0; j < 8; j++) o[j] = f2b(xa[s4*8 + j]);
    *(uint4*)(x2 + (size_t)row*CC + h*32 + s4*8) = *(uint4*)o;
  }
}

// ---------------- launcher ----------------
extern "C" void kernel_launch(void* const* d_in, const int* in_sizes, int n_in,
                              void* d_out, int out_size, void* d_ws, size_t ws_size,
                              hipStream_t stream)
{
  // bind inputs BY SIZE (validated rounds 10-17)
  int ix=-1, iwqkv=-1, iwpq=-1, iwpkv=-1, iwproj=-1, ib=-1;
  for (int i = 0; i < n_in; i++){
    switch (in_sizes[i]){
      case 4710400: ix = i; break;
      case 196608:  iwqkv = i; break;
      case 131072:  iwpkv = i; break;
      case 256:     ib = i; break;
      case 65536:   if (iwpq < 0) iwpq = i; else iwproj = i; break;
      default: break;
    }
  }
  if (ix < 0 || iwqkv < 0 || iwpq < 0 || iwpkv < 0 || iwproj < 0 || ib < 0){
    ix=0; iwqkv=1; iwpq=2; iwpkv=3; iwproj=4; ib=5;
  }
  const float* x     = (const float*)d_in[ix];
  const float* Wqkv  = (const float*)d_in[iwqkv];
  const float* Wpq   = (const float*)d_in[iwpq];
  const float* Wpkv  = (const float*)d_in[iwpkv];
  const float* Wproj = (const float*)d_in[iwproj];
  const float* bproj = (const float*)d_in[ib];

  char* ws = (char*)d_ws;
  if (ws_size < 208269312ULL) return;

  short* wq    = (short*)(ws + 0);               // 768*256
  short* wpq   = (short*)(ws + 393216);          // 256*256
  short* wpkv  = (short*)(ws + 524288);          // 512*256
  short* wprj  = (short*)(ws + 786432);          // 256*256
  short* xb    = (short*)(ws + 917504);          // 18400x256
  short* qkv   = (short*)(ws + 10338304);        // 18408x768 (8 slack rows zeroed)
  short* vt    = (short*)(ws + 38612992);        // 20x256x928
  short* x1    = (short*)(ws + 48115712);        // 92000x256
  short* xd    = (short*)(ws + 95219712);        // 18400x256
  short* k2v2  = (short*)(ws + 104640512);       // 92000x512
  short* q2b   = (short*)(ws + 198848512);       // 18400x256 -> end 208,269,312
  short* x2    = xb;                             // alias: xb dead after QKV GEMM

  float* outp  = (float*)d_out;                  // f32 out   [0 : 4,710,400)
  float* attnp = outp + 4710400;                 // f32 attn  [4,710,400 : 5,446,400)

  k18_cast<<<dim3(768), dim3(256), 0, stream>>>(Wqkv,  wq,   196608);
  k18_cast<<<dim3(256), dim3(256), 0, stream>>>(Wpq,   wpq,  65536);
  k18_cast<<<dim3(512), dim3(256), 0, stream>>>(Wpkv,  wpkv, 131072);
  k18_cast<<<dim3(256), dim3(256), 0, stream>>>(Wproj, wprj, 65536);
  k18_make_xb<<<dim3(4600), dim3(256), 0, stream>>>(x, xb);
  k18_zero<<<dim3(24), dim3(256), 0, stream>>>(qkv + (size_t)MROWS*768, 6144);

  // qkv = xb @ Wqkv^T           (MFMA)
  k18_gemm<0><<<dim3(144, 6), dim3(256), 0, stream>>>(xb, wq, qkv, nullptr, nullptr, MROWS, 256, 768, 1.0f);
  // V transpose for flash
  k18_vt<<<dim3(15, 4, 20), dim3(256), 0, stream>>>(qkv, vt);
  // stage-1 flash attention v7  (R16 + T12: P in registers)
  k18_flash<<<dim3(36, 5, 4), dim3(256), 0, stream>>>(qkv, vt, x1, xd);
  // kv2 = x1 @ Wpkv^T           (MFMA)
  k18_gemm<0><<<dim3(719, 4), dim3(256), 0, stream>>>(x1, wpkv, k2v2, nullptr, nullptr, M2ROWS, 256, 512, 1.0f);
  // q2 = xd @ Wpq^T * scale     (MFMA)
  k18_gemm<0><<<dim3(144, 2), dim3(256), 0, stream>>>(xd, wpq, q2b, nullptr, nullptr, MROWS, 256, 256, SCALE);
  // stage-2 attention (f32 attn, bf16 x2)
  k18_attn2<<<dim3(575), dim3(256), 0, stream>>>(q2b, k2v2, attnp, x2);
  // out = x2 @ Wproj^T + bias   (MFMA, f32 permuted store)
  k18_gemm<1><<<dim3(144, 2), dim3(256), 0, stream>>>(x2, wprj, nullptr, outp, bproj, MROWS, 256, 256, 1.0f);
}

// Round 19
// 322.510 us; speedup vs baseline: 1.6352x; 1.3047x over previous
//
#include <hip/hip_runtime.h>
#include <stdint.h>

#define PP 920
#define FF 5
#define BBATCH 4
#define CC 256
#define NN 4600          // FF*PP
#define HH 8
#define MROWS 18400      // BBATCH*NN
#define M2ROWS 92000     // BBATCH*NN*FF
#define SCALE 0.17677669529663687f

// EVIDENCE LOG:
//  - Inputs f32 bound BY SIZE; outputs f32: out=d_out[0:4710400), attn=[4710400:5446400).
//  - R12 (16x16, QT=64, 1440 blocks): flash 208us, occ 20.5% (104V+64A=168 -> 3 waves/SIMD),
//    conflicts 2.47e7 — all from Ps[64][32] 64B-stride fragment reads.
//  - R16-R18 (32x32): o[8]=128 AGPR + ~156 VGPR = 284 > 256 -> 1 wave/SIMD (occ 10.9%),
//    latency fully exposed; 227-291us regardless of conflicts/LDS/spill fixes.
//    LESSON: count AGPRs (unified file!) — VGPR_Count in CSV excludes them.
//  - R19 = R12 + Ps padded to [64][40] (8-way -> 2-way free) + mid-barrier deleted
//    (per-wave Ps rows; same-wave DS ordering HW-validated R15/R17). 2 barriers/chunk.

typedef short bf16x8 __attribute__((ext_vector_type(8)));
typedef float f32x4 __attribute__((ext_vector_type(4)));
typedef uint32_t u32;

#define MFMA16 __builtin_amdgcn_mfma_f32_16x16x32_bf16

__device__ __forceinline__ float b2f(unsigned short s){
  u32 u = ((u32)s) << 16; float f; __builtin_memcpy(&f, &u, 4); return f;
}
__device__ __forceinline__ unsigned short f2b(float f){
  u32 u; __builtin_memcpy(&u, &f, 4);
  u = (u + 0x7FFFu + ((u >> 16) & 1u)) >> 16;   // round-to-nearest-even
  return (unsigned short)u;
}

// ---------------- prep ----------------

__global__ void k19_cast(const float* __restrict__ in, short* __restrict__ out, int n){
  int i = blockIdx.x*256 + threadIdx.x;
  if (i < n) out[i] = (short)f2b(in[i]);
}

__global__ void k19_make_xb(const float* __restrict__ x, short* __restrict__ xb){
  int i = blockIdx.x*256 + threadIdx.x;       // one thread per 4 elems
  long e0 = (long)i*4;
  if (e0 >= (long)MROWS*CC) return;
  int row = (int)(e0 >> 8); int c = (int)(e0 & 255);
  int b = row / NN; int s = row - b*NN; int f = s / PP; int p = s - f*PP;
  const float4 v = *(const float4*)(x + ((size_t)(p*(BBATCH*FF) + b*FF + f))*CC + c);
  unsigned short o[4];
  o[0]=f2b(v.x); o[1]=f2b(v.y); o[2]=f2b(v.z); o[3]=f2b(v.w);
  *(ushort4*)(xb + e0) = *(ushort4*)o;
}

__global__ void k19_zero(short* p, int n){
  int i = blockIdx.x*256 + threadIdx.x;
  if (i < n) p[i] = 0;
}

// ---------------- MFMA GEMM (unchanged — passed R12-R18) ----------------
template<int MODE>
__launch_bounds__(256)
__global__ void k19_gemm(const short* __restrict__ A, const short* __restrict__ Bw,
                         short* __restrict__ Cout, float* __restrict__ FCout,
                         const float* __restrict__ bias,
                         int M, int lda, int ldc, float alpha)
{
  __shared__ short As[128][40];
  __shared__ short Bs[128][40];
  const int tid = threadIdx.x;
  const int m0 = blockIdx.x*128, n0 = blockIdx.y*128;
  const int w = tid >> 6, l = tid & 63;
  const int wm = (w >> 1)*64, wn = (w & 1)*64;
  const int lr = l & 15, lg = l >> 4;

  f32x4 acc[4][4] = {};

  for (int k0 = 0; k0 < 256; k0 += 32){
    #pragma unroll
    for (int i = 0; i < 2; i++){
      int v = tid + 256*i;               // 0..511
      int ar = v >> 2, as = (v & 3)*8;
      int grow = m0 + ar; if (grow >= M) grow = M - 1;
      *(uint4*)(&As[ar][as]) = *(const uint4*)(A + (size_t)grow*lda + k0 + as);
      *(uint4*)(&Bs[ar][as]) = *(const uint4*)(Bw + (size_t)(n0 + ar)*256 + k0 + as);
    }
    __syncthreads();
    bf16x8 af[4], bfr[4];
    #pragma unroll
    for (int i = 0; i < 4; i++) af[i]  = *(const bf16x8*)(&As[wm + i*16 + lr][lg*8]);
    #pragma unroll
    for (int j = 0; j < 4; j++) bfr[j] = *(const bf16x8*)(&Bs[wn + j*16 + lr][lg*8]);
    #pragma unroll
    for (int i = 0; i < 4; i++)
      #pragma unroll
      for (int j = 0; j < 4; j++)
        acc[i][j] = MFMA16(af[i], bfr[j], acc[i][j], 0, 0, 0);
    __syncthreads();
  }

  #pragma unroll
  for (int i = 0; i < 4; i++){
    #pragma unroll
    for (int r = 0; r < 4; r++){
      int m = m0 + wm + i*16 + lg*4 + r;
      if (m >= M) continue;
      #pragma unroll
      for (int j = 0; j < 4; j++){
        int n = n0 + wn + j*16 + lr;
        float v = acc[i][j][r]*alpha;
        if (MODE == 1){
          v += bias[n];
          int b = m / NN, s = m - b*NN; int f = s / PP, p = s - f*PP;
          FCout[(size_t)(p*(BBATCH*FF) + b*FF + f)*CC + n] = v;    // f32 store
        } else {
          Cout[(size_t)m*ldc + n] = (short)f2b(v);
        }
      }
    }
  }
}

// ---------------- V transpose (unchanged) ----------------
__launch_bounds__(256)
__global__ void k19_vt(const short* __restrict__ qkv, short* __restrict__ vt){
  __shared__ short t[64][80];
  const int p0 = blockIdx.x*64;
  const int c0 = blockIdx.y*64;
  const int bf = blockIdx.z;
  const int b = bf / FF, f = bf - b*FF;
  const int tid = threadIdx.x;
  #pragma unroll
  for (int i = 0; i < 2; i++){
    int v = tid + 256*i;                 // 0..511
    int pr = v >> 3, sg = (v & 7)*8;
    uint4 val = make_uint4(0,0,0,0);
    int p = p0 + pr;
    if (p < PP)
      val = *(const uint4*)(qkv + ((size_t)(b*NN + f*PP + p))*768 + 512 + c0 + sg);
    *(uint4*)(&t[pr][sg]) = val;
  }
  __syncthreads();
  #pragma unroll
  for (int i = 0; i < 2; i++){
    int v = tid + 256*i;
    int cr = v & 63, pg = v >> 6;        // pg 0..7
    int pbase = p0 + pg*8;
    if (pbase < 928){
      unsigned short o[8];
      #pragma unroll
      for (int jj = 0; jj < 8; jj++) o[jj] = (unsigned short)t[pg*8 + jj][cr];
      *(uint4*)(vt + ((size_t)(bf*CC + c0 + cr))*928 + pbase) = *(uint4*)o;
    }
  }
}

// ---------------- Stage-1 flash v8 = R12 + padded Ps + no mid-barrier ----------------
// grid (72, 5, 4): q-tile(64), key-frame f, batch b. 4 waves; wave w owns q rows w*16..+15.
// Register budget: qf 32V + o 64A + temps -> ~104V+64A = 168 -> 3 waves/SIMD.
__launch_bounds__(256)
__global__ void k19_flash(const short* __restrict__ qkv, const short* __restrict__ vt,
                          short* __restrict__ x1, short* __restrict__ xd)
{
  __shared__ short Ks[32][264];   // 32 keys x 256 dims (+8 pad)
  __shared__ short Vs[256][40];   // 256 c x 32 keys (+8 pad)
  __shared__ short Ps[64][40];    // P tile, PADDED to 80B rows (R12 had [32]: 8-way conflicts)

  const int qt = blockIdx.x, f = blockIdx.y, b = blockIdx.z;
  const int tid = threadIdx.x, w = tid >> 6, l = tid & 63;
  const int lr = l & 15, lg = l >> 4;
  const int qbase = qt*64;

  bf16x8 qf[8];
  {
    int qrow = qbase + w*16 + lr; if (qrow > NN - 1) qrow = NN - 1;
    const short* qp = qkv + (size_t)(b*NN + qrow)*768;
    #pragma unroll
    for (int kc = 0; kc < 8; kc++) qf[kc] = *(const bf16x8*)(qp + kc*32 + lg*8);
  }

  f32x4 o[16] = {};
  float den[4] = {0.f, 0.f, 0.f, 0.f};

  const size_t krow0 = (size_t)(b*NN + f*PP)*768 + 256;
  const short* vtp = vt + (size_t)((b*FF + f)*CC)*928;

  for (int ch = 0; ch < 29; ch++){
    const int key0 = ch*32;
    #pragma unroll
    for (int i = 0; i < 4; i++){
      int v = tid + 256*i;                   // 0..1023
      int kr = v >> 5, ks = (v & 31)*8;
      *(uint4*)(&Ks[kr][ks]) = *(const uint4*)(qkv + krow0 + (size_t)(key0 + kr)*768 + ks);
    }
    {
      const short* vp = vtp + (size_t)tid*928 + key0;
      #pragma unroll
      for (int i = 0; i < 4; i++)
        *(uint4*)(&Vs[tid][i*8]) = *(const uint4*)(vp + i*8);
    }
    __syncthreads();

    f32x4 s0 = {}, s1 = {};
    #pragma unroll
    for (int kc = 0; kc < 8; kc++){
      bf16x8 k0v = *(const bf16x8*)(&Ks[lr][kc*32 + lg*8]);
      bf16x8 k1v = *(const bf16x8*)(&Ks[16 + lr][kc*32 + lg*8]);
      s0 = MFMA16(qf[kc], k0v, s0, 0, 0, 0);
      s1 = MFMA16(qf[kc], k1v, s1, 0, 0, 0);
    }

    // fixed-max softmax numerators (|logit| bounded ~1.7 on this data)
    #pragma unroll
    for (int r = 0; r < 4; r++){
      float v0 = s0[r]*SCALE, v1 = s1[r]*SCALE;
      if (key0 + lr      >= PP) v0 = -1e30f;
      if (key0 + 16 + lr >= PP) v1 = -1e30f;
      float p0 = __expf(v0);
      float p1 = __expf(v1);
      den[r] += p0 + p1;
      int qlocal = w*16 + lg*4 + r;
      Ps[qlocal][lr]      = (short)f2b(p0);
      Ps[qlocal][16 + lr] = (short)f2b(p1);
    }
    // NO barrier: wave w writes AND reads only Ps rows w*16..w*16+15
    // (same-wave DS ordering; pattern HW-validated by R15/R17 passes)

    bf16x8 pa = *(const bf16x8*)(&Ps[w*16 + lr][lg*8]);
    #pragma unroll
    for (int ct = 0; ct < 16; ct++){
      bf16x8 vb = *(const bf16x8*)(&Vs[ct*16 + lr][lg*8]);
      o[ct] = MFMA16(pa, vb, o[ct], 0, 0, 0);
    }
    __syncthreads();   // protect Ks/Vs before next staging
  }

  #pragma unroll
  for (int r = 0; r < 4; r++){
    float dsum = den[r];
    #pragma unroll
    for (int off = 8; off >= 1; off >>= 1) dsum += __shfl_xor(dsum, off);
    float inv = 1.f/dsum;
    int srow = qbase + w*16 + lg*4 + r;
    if (srow >= NN) continue;
    bool dg = (srow/PP == f);
    size_t x1base = ((size_t)(b*NN + srow)*FF + f)*CC;
    size_t xdbase = (size_t)(b*NN + srow)*CC;
    #pragma unroll
    for (int ct = 0; ct < 16; ct++){
      short val = (short)f2b(o[ct][r]*inv);
      x1[x1base + ct*16 + lr] = val;
      if (dg) xd[xdbase + ct*16 + lr] = val;
    }
  }
}

// ---------------- Stage-2 attention (unchanged — passed R12-R18) ----------------
__launch_bounds__(256)
__global__ void k19_attn2(const short* __restrict__ q2b, const short* __restrict__ k2v2,
                          float* __restrict__ attnp, short* __restrict__ x2)
{
  int idx = blockIdx.x*256 + threadIdx.x;
  if (idx >= MROWS*HH) return;
  const int h = idx & 7; const int row = idx >> 3;   // row = b*N + s

  float qv[32];
  {
    const short* qp = q2b + (size_t)row*CC + h*32;
    #pragma unroll
    for (int s4 = 0; s4 < 4; s4++){
      uint4 u = *(const uint4*)(qp + s4*8);
      const unsigned short* sp = (const unsigned short*)&u;
      #pragma unroll
      for (int j = 0; j < 8; j++) qv[s4*8 + j] = b2f(sp[j]);
    }
  }

  float lgt[FF];
  #pragma unroll
  for (int f = 0; f < FF; f++){
    const short* kp = k2v2 + ((size_t)row*FF + f)*512 + h*32;
    float a = 0.f;
    #pragma unroll
    for (int s4 = 0; s4 < 4; s4++){
      uint4 u = *(const uint4*)(kp + s4*8);
      const unsigned short* sp = (const unsigned short*)&u;
      #pragma unroll
      for (int j = 0; j < 8; j++) a += qv[s4*8 + j]*b2f(sp[j]);
    }
    lgt[f] = a;
  }

  float mx = lgt[0];
  #pragma unroll
  for (int f = 1; f < FF; f++) mx = fmaxf(mx, lgt[f]);
  float pr[FF], ps = 0.f;
  #pragma unroll
  for (int f = 0; f < FF; f++){ pr[f] = __expf(lgt[f] - mx); ps += pr[f]; }
  float inv = 1.f/ps;

  const int b = row / NN; const int s = row - b*NN;
  size_t ab = (((size_t)(b*HH + h))*NN + s)*FF;
  #pragma unroll
  for (int f = 0; f < FF; f++) attnp[ab + f] = pr[f]*inv;   // f32 store

  float xa[32] = {};
  #pragma unroll
  for (int f = 0; f < FF; f++){
    const short* vp = k2v2 + ((size_t)row*FF + f)*512 + 256 + h*32;
    float wgt = pr[f]*inv;
    #pragma unroll
    for (int s4 = 0; s4 < 4; s4++){
      uint4 u = *(const uint4*)(vp + s4*8);
      const unsigned short* sp = (const unsigned short*)&u;
      #pragma unroll
      for (int j = 0; j < 8; j++) xa[s4*8 + j] += wgt*b2f(sp[j]);
    }
  }
  #pragma unroll
  for (int s4 = 0; s4 < 4; s4++){
    unsigned short o[8];
    #pragma unroll
    for (int j = 0; j < 8; j++) o[j] = f2b(xa[s4*8 + j]);
    *(uint4*)(x2 + (size_t)row*CC + h*32 + s4*8) = *(uint4*)o;
  }
}

// ---------------- launcher ----------------
extern "C" void kernel_launch(void* const* d_in, const int* in_sizes, int n_in,
                              void* d_out, int out_size, void* d_ws, size_t ws_size,
                              hipStream_t stream)
{
  // bind inputs BY SIZE (validated rounds 10-18)
  int ix=-1, iwqkv=-1, iwpq=-1, iwpkv=-1, iwproj=-1, ib=-1;
  for (int i = 0; i < n_in; i++){
    switch (in_sizes[i]){
      case 4710400: ix = i; break;
      case 196608:  iwqkv = i; break;
      case 131072:  iwpkv = i; break;
      case 256:     ib = i; break;
      case 65536:   if (iwpq < 0) iwpq = i; else iwproj = i; break;
      default: break;
    }
  }
  if (ix < 0 || iwqkv < 0 || iwpq < 0 || iwpkv < 0 || iwproj < 0 || ib < 0){
    ix=0; iwqkv=1; iwpq=2; iwpkv=3; iwproj=4; ib=5;
  }
  const float* x     = (const float*)d_in[ix];
  const float* Wqkv  = (const float*)d_in[iwqkv];
  const float* Wpq   = (const float*)d_in[iwpq];
  const float* Wpkv  = (const float*)d_in[iwpkv];
  const float* Wproj = (const float*)d_in[iwproj];
  const float* bproj = (const float*)d_in[ib];

  char* ws = (char*)d_ws;
  if (ws_size < 208269312ULL) return;

  short* wq    = (short*)(ws + 0);               // 768*256
  short* wpq   = (short*)(ws + 393216);          // 256*256
  short* wpkv  = (short*)(ws + 524288);          // 512*256
  short* wprj  = (short*)(ws + 786432);          // 256*256
  short* xb    = (short*)(ws + 917504);          // 18400x256
  short* qkv   = (short*)(ws + 10338304);        // 18408x768 (8 slack rows zeroed)
  short* vt    = (short*)(ws + 38612992);        // 20x256x928
  short* x1    = (short*)(ws + 48115712);        // 92000x256
  short* xd    = (short*)(ws + 95219712);        // 18400x256
  short* k2v2  = (short*)(ws + 104640512);       // 92000x512
  short* q2b   = (short*)(ws + 198848512);       // 18400x256 -> end 208,269,312
  short* x2    = xb;                             // alias: xb dead after QKV GEMM

  float* outp  = (float*)d_out;                  // f32 out   [0 : 4,710,400)
  float* attnp = outp + 4710400;                 // f32 attn  [4,710,400 : 5,446,400)

  k19_cast<<<dim3(768), dim3(256), 0, stream>>>(Wqkv,  wq,   196608);
  k19_cast<<<dim3(256), dim3(256), 0, stream>>>(Wpq,   wpq,  65536);
  k19_cast<<<dim3(512), dim3(256), 0, stream>>>(Wpkv,  wpkv, 131072);
  k19_cast<<<dim3(256), dim3(256), 0, stream>>>(Wproj, wprj, 65536);
  k19_make_xb<<<dim3(4600), dim3(256), 0, stream>>>(x, xb);
  k19_zero<<<dim3(24), dim3(256), 0, stream>>>(qkv + (size_t)MROWS*768, 6144);

  // qkv = xb @ Wqkv^T           (MFMA)
  k19_gemm<0><<<dim3(144, 6), dim3(256), 0, stream>>>(xb, wq, qkv, nullptr, nullptr, MROWS, 256, 768, 1.0f);
  // V transpose for flash
  k19_vt<<<dim3(15, 4, 20), dim3(256), 0, stream>>>(qkv, vt);
  // stage-1 flash attention v8  (R12 + padded Ps + 2 barriers/chunk)
  k19_flash<<<dim3(72, 5, 4), dim3(256), 0, stream>>>(qkv, vt, x1, xd);
  // kv2 = x1 @ Wpkv^T           (MFMA)
  k19_gemm<0><<<dim3(719, 4), dim3(256), 0, stream>>>(x1, wpkv, k2v2, nullptr, nullptr, M2ROWS, 256, 512, 1.0f);
  // q2 = xd @ Wpq^T * scale     (MFMA)
  k19_gemm<0><<<dim3(144, 2), dim3(256), 0, stream>>>(xd, wpq, q2b, nullptr, nullptr, MROWS, 256, 256, SCALE);
  // stage-2 attention (f32 attn, bf16 x2)
  k19_attn2<<<dim3(575), dim3(256), 0, stream>>>(q2b, k2v2, attnp, x2);
  // out = x2 @ Wproj^T + bias   (MFMA, f32 permuted store)
  k19_gemm<1><<<dim3(144, 2), dim3(256), 0, stream>>>(x2, wprj, nullptr, outp, bproj, MROWS, 256, 256, 1.0f);
}